// Round 4
// baseline (39.135 us; speedup 1.0000x reference)
//
#include <hip/hip_runtime.h>

#define KL   19
#define K2   361
#define W    256
#define H    256
#define HW   65536
#define C    3
#define PADL 9
#define B    2
#define TC   34            // tile cols: 16 pixels + 18 halo
#define TR   22            // tile rows: 4 pixel rows + 18 halo
#define TPOS (TR * TC)     // 748 spatial positions

// One block = 16 cols x 4 rows = 64 output pixels. The shared 22x34 input
// window (x3 channels, channel-interleaved [pos][4]) is staged once with
// fused reflection; the r-loop reuses it for 4 pixel rows, amortizing the
// staging 4x vs the previous 1-row tile. 16 lanes per pixel stream that
// pixel's 19x19 kernel row (coalesced dwords, one base + imm offsets).
__global__ __launch_bounds__(256, 8) void blur_fused(
    const float* __restrict__ in,     // (B, C, 256, 256)
    const float* __restrict__ kern,   // (B, HW, 19, 19)
    float* __restrict__ out)          // (B, C, 256, 256)
{
    __shared__ float tile[TPOS * 4];  // 11968 B

    const int tid = threadIdx.x;
    const int bid = blockIdx.x;
    const int b   = bid >> 10;             // / 1024 (64 row-blocks * 16 col-blocks)
    const int rem = bid & 1023;
    const int i0  = (rem >> 4) << 2;       // row-block * 4
    const int j0  = (rem & 15) << 4;       // col-block * 16

    // ---- stage 22x34x3 input window with fused reflection ----
    const float* in_b = in + (size_t)b * (C * HW);
    for (int s = tid; s < TPOS * 4; s += 256) {
        const int ch  = s & 3;             // ch==3 lanes idle (keeps writes linear)
        const int pos = s >> 2;
        if (ch < 3) {
            const int r  = pos / TC;
            const int cc = pos - r * TC;
            int ro = i0 + r - PADL;                    // [-9, 264]
            ro = (ro < 0) ? -ro : ro;
            ro = (ro > H - 1) ? 2 * (H - 1) - ro : ro;
            int co = j0 + cc - PADL;
            co = (co < 0) ? -co : co;
            co = (co > W - 1) ? 2 * (W - 1) - co : co;
            tile[s] = in_b[ch * HW + ro * W + co];
        }
    }
    __syncthreads();

    const int sub = tid & 15;              // lane within pixel group
    const int q   = tid >> 4;              // pixel column within block
    const float scale = 1.0f / (float)K2;

    #pragma unroll
    for (int r = 0; r < 4; ++r) {
        const int p = (i0 + r) * W + j0 + q;               // index within HW
        const float* krow = kern + ((size_t)b * HW + p) * K2 + sub;

        // preload all 23 weights (single base + compile-time offsets)
        float w[23];
        #pragma unroll
        for (int c = 0; c < 23; ++c) {
            const int t = sub + 16 * c;
            w[c] = (t < K2) ? krow[16 * c] : 0.f;          // guarded only c==22
        }

        float a0 = 0.f, a1 = 0.f, a2 = 0.f;
        #pragma unroll
        for (int c = 0; c < 23; ++c) {
            int t = sub + 16 * c;
            if (t > K2 - 1) t = K2 - 1;                    // clamp (w==0 there)
            const int ki = t / KL;
            const int kj = t - ki * KL;
            const float* src = &tile[((ki + r) * TC + kj + q) * 4];
            a0 += w[c] * src[0];
            a1 += w[c] * src[1];
            a2 += w[c] * src[2];
        }

        #pragma unroll
        for (int o = 8; o >= 1; o >>= 1) {
            a0 += __shfl_xor(a0, o, 16);
            a1 += __shfl_xor(a1, o, 16);
            a2 += __shfl_xor(a2, o, 16);
        }

        if (sub == 0) {
            float* ob = out + (size_t)b * (C * HW) + p;
            ob[0]      = a0 * scale;
            ob[HW]     = a1 * scale;
            ob[2 * HW] = a2 * scale;
        }
    }
}

extern "C" void kernel_launch(void* const* d_in, const int* in_sizes, int n_in,
                              void* d_out, int out_size, void* d_ws, size_t ws_size,
                              hipStream_t stream) {
    const float* in   = (const float*)d_in[0];
    const float* kern = (const float*)d_in[1];
    float* out        = (float*)d_out;

    dim3 grid(B * (H / 4) * (W / 16)), block(256);   // 2048 blocks, 64 px each
    hipLaunchKernelGGL(blur_fused, grid, block, 0, stream, in, kern, out);
}

// Round 5
// 37.564 us; speedup vs baseline: 1.0418x; 1.0418x over previous
//
#include <hip/hip_runtime.h>

#define KL   19
#define K2   361
#define W    256
#define H    256
#define HW   65536
#define C    3
#define PADL 9
#define B    2
#define TC   34            // tile cols: 16 pixels + 18 halo
#define TPOS (KL * TC)     // 646 spatial positions

// Sum across each 16-lane DPP row via v_add_f32 row_shr:{1,2,4,8}.
// Lane 15 of each row holds the full 16-lane sum. old=0 makes invalid
// source lanes contribute 0 regardless of bound_ctrl convention.
__device__ __forceinline__ float dpp_sum16(float x) {
    int t;
    t = __builtin_amdgcn_update_dpp(0, __float_as_int(x), 0x111, 0xF, 0xF, true); // row_shr:1
    x += __int_as_float(t);
    t = __builtin_amdgcn_update_dpp(0, __float_as_int(x), 0x112, 0xF, 0xF, true); // row_shr:2
    x += __int_as_float(t);
    t = __builtin_amdgcn_update_dpp(0, __float_as_int(x), 0x114, 0xF, 0xF, true); // row_shr:4
    x += __int_as_float(t);
    t = __builtin_amdgcn_update_dpp(0, __float_as_int(x), 0x118, 0xF, 0xF, true); // row_shr:8
    x += __int_as_float(t);
    return x;
}

// One block = 16 consecutive pixels of one row (R3 geometry: 8192 blocks,
// 32 blocks/CU oversubscription hides staging). 16 lanes per pixel stream
// that pixel's 19x19 kernel (coalesced dwords, one base + imm offsets).
// Shared 19x34 input window lives in LDS channel-interleaved [pos][4] so
// each tap is ONE 16B-aligned ds_read of 3 floats. Reduction is DPP (VALU),
// not shuffles (DS) — kills the 12-op serial DS tail per row.
__global__ __launch_bounds__(256, 8) void blur_fused(
    const float* __restrict__ in,     // (B, C, 256, 256)
    const float* __restrict__ kern,   // (B, HW, 19, 19)
    float* __restrict__ out)          // (B, C, 256, 256)
{
    __shared__ float tile[TPOS * 4];  // 10336 B

    const int tid = threadIdx.x;
    const int pb  = blockIdx.x << 4;      // first pixel of block
    const int b   = pb >> 16;
    const int i   = (pb >> 8) & 255;      // row
    const int j0  = pb & 255;             // first col

    // ---- stage 19x34x3 input window with fused reflection ----
    const float* in_b = in + (size_t)b * (C * HW);
    for (int s = tid; s < TPOS * 4; s += 256) {
        const int ch  = s & 3;            // ch==3 lanes idle (writes stay linear)
        const int pos = s >> 2;
        if (ch < 3) {
            const int r  = pos / TC;
            const int cc = pos - r * TC;
            int ro = i + r - PADL;                     // [-9, 264]
            ro = (ro < 0) ? -ro : ro;
            ro = (ro > H - 1) ? 2 * (H - 1) - ro : ro;
            int co = j0 + cc - PADL;
            co = (co < 0) ? -co : co;
            co = (co > W - 1) ? 2 * (W - 1) - co : co;
            tile[s] = in_b[ch * HW + ro * W + co];
        }
    }
    __syncthreads();

    const int sub = tid & 15;
    const int q   = tid >> 4;
    const int p   = pb + q;
    const float* krow = kern + (size_t)p * K2 + sub;

    // ---- preload all 23 weights (23 coalesced loads in flight) ----
    float w[23];
    #pragma unroll
    for (int c = 0; c < 23; ++c) {
        const int t = sub + 16 * c;
        w[c] = (t < K2) ? krow[16 * c] : 0.f;          // guarded only c==22
    }

    // ---- accumulate from LDS ----
    float a0 = 0.f, a1 = 0.f, a2 = 0.f;
    #pragma unroll
    for (int c = 0; c < 23; ++c) {
        int t = sub + 16 * c;
        if (t > K2 - 1) t = K2 - 1;                    // clamp (w==0 there)
        const int ki = t / KL;
        const int kj = t - ki * KL;
        const float* src = &tile[(ki * TC + kj + q) * 4];
        a0 += w[c] * src[0];
        a1 += w[c] * src[1];
        a2 += w[c] * src[2];
    }

    // ---- DPP reduction (VALU pipe); lane sub==15 holds each sum ----
    a0 = dpp_sum16(a0);
    a1 = dpp_sum16(a1);
    a2 = dpp_sum16(a2);

    if (sub == 15) {
        const float s = 1.0f / (float)K2;
        float* ob = out + (size_t)b * (C * HW) + (p & 0xFFFF);
        ob[0]      = a0 * s;
        ob[HW]     = a1 * s;
        ob[2 * HW] = a2 * s;
    }
}

extern "C" void kernel_launch(void* const* d_in, const int* in_sizes, int n_in,
                              void* d_out, int out_size, void* d_ws, size_t ws_size,
                              hipStream_t stream) {
    const float* in   = (const float*)d_in[0];
    const float* kern = (const float*)d_in[1];
    float* out        = (float*)d_out;

    const int npix = B * HW;                 // 131072
    dim3 grid(npix / 16), block(256);        // 8192 blocks
    hipLaunchKernelGGL(blur_fused, grid, block, 0, stream, in, kern, out);
}

// Round 6
// 35.070 us; speedup vs baseline: 1.1159x; 1.0711x over previous
//
#include <hip/hip_runtime.h>

#define KL   19
#define K2   361
#define W    256
#define H    256
#define HW   65536
#define C    3
#define PADL 9
#define B    2
#define TC   34            // tile cols: 16 pixels + 18 halo
#define TR   20            // tile rows: 2 pixel rows + 18 halo
#define TPOS (TR * TC)     // 680 spatial positions

// Sum across each 16-lane DPP row via v_add_f32 row_shr:{1,2,4,8}.
// Lane 15 of each row holds the full 16-lane sum.
__device__ __forceinline__ float dpp_sum16(float x) {
    int t;
    t = __builtin_amdgcn_update_dpp(0, __float_as_int(x), 0x111, 0xF, 0xF, true); // row_shr:1
    x += __int_as_float(t);
    t = __builtin_amdgcn_update_dpp(0, __float_as_int(x), 0x112, 0xF, 0xF, true); // row_shr:2
    x += __int_as_float(t);
    t = __builtin_amdgcn_update_dpp(0, __float_as_int(x), 0x114, 0xF, 0xF, true); // row_shr:4
    x += __int_as_float(t);
    t = __builtin_amdgcn_update_dpp(0, __float_as_int(x), 0x118, 0xF, 0xF, true); // row_shr:8
    x += __int_as_float(t);
    return x;
}

// One block = 16 cols x 2 rows = 32 output pixels (4096 blocks). The shared
// 20x34x3 window is staged once (plane-major for coalesced global reads,
// channel-interleaved [pos][4] in LDS) and reused by two sequential passes,
// halving per-pixel staging cost vs the 1-row tile. 16 lanes per pixel
// stream that pixel's 19x19 kernel (coalesced dwords, one base + imm
// offsets, 23-deep load burst). DPP (VALU) reduction, no DS shuffles.
// NOTE: passes use separate, sequential w[23] bursts — overlapping live
// ranges at the (256,8) 64-VGPR cap caused R4's spill regression.
__global__ __launch_bounds__(256, 8) void blur_fused(
    const float* __restrict__ in,     // (B, C, 256, 256)
    const float* __restrict__ kern,   // (B, HW, 19, 19)
    float* __restrict__ out)          // (B, C, 256, 256)
{
    __shared__ float tile[TPOS * 4];  // 10880 B

    const int tid = threadIdx.x;
    const int bid = blockIdx.x;
    const int b   = bid >> 11;             // 2048 blocks per batch
    const int rem = bid & 2047;
    const int i0  = (rem >> 4) << 1;       // row-pair base (0,2,...,254)
    const int j0  = (rem & 15) << 4;       // col base (multiple of 16)

    // ---- stage 20x34x3 window, plane-major (coalesced 256B per inst) ----
    const float* in_b = in + (size_t)b * (C * HW);
    #pragma unroll
    for (int k = 0; k < 8; ++k) {
        const int s = tid + 256 * k;       // 0..2047
        if (s < TPOS * 3) {                // 2040 useful slots
            const int ch  = s / TPOS;      // plane index 0..2 (magic-mul)
            const int pos = s - ch * TPOS;
            const int rr  = pos / TC;
            const int cc  = pos - rr * TC;
            int ro = i0 + rr - PADL;                   // [-9, 264]
            ro = (ro < 0) ? -ro : ro;
            ro = (ro > H - 1) ? 2 * (H - 1) - ro : ro;
            int co = j0 + cc - PADL;
            co = (co < 0) ? -co : co;
            co = (co > W - 1) ? 2 * (W - 1) - co : co;
            tile[4 * pos + ch] = in_b[ch * HW + ro * W + co];
        }
    }
    __syncthreads();

    const int sub = tid & 15;              // lane within pixel group
    const int q   = tid >> 4;              // pixel column within block
    const float scale = 1.0f / (float)K2;

    #pragma unroll
    for (int r = 0; r < 2; ++r) {          // two pixel rows share the tile
        const int ij = ((i0 + r) << 8) + j0 + q;
        const float* krow = kern + ((size_t)b * HW + ij) * K2 + sub;

        // preload all 23 weights (coalesced: 4 full cache lines / wave-inst)
        float w[23];
        #pragma unroll
        for (int c = 0; c < 23; ++c) {
            const int t = sub + 16 * c;
            w[c] = (t < K2) ? krow[16 * c] : 0.f;      // guard only c==22
        }

        float a0 = 0.f, a1 = 0.f, a2 = 0.f;
        #pragma unroll
        for (int c = 0; c < 23; ++c) {
            int t = sub + 16 * c;
            if (t > K2 - 1) t = K2 - 1;                // clamp (w==0 there)
            const int ki = t / KL;
            const int kj = t - ki * KL;
            // r*TC folds into the ds_read immediate offset (544*r bytes)
            const float* src = &tile[((ki + r) * TC + kj + q) * 4];
            a0 += w[c] * src[0];
            a1 += w[c] * src[1];
            a2 += w[c] * src[2];
        }

        a0 = dpp_sum16(a0);
        a1 = dpp_sum16(a1);
        a2 = dpp_sum16(a2);

        if (sub == 15) {
            float* ob = out + (size_t)b * (C * HW) + ij;
            ob[0]      = a0 * scale;
            ob[HW]     = a1 * scale;
            ob[2 * HW] = a2 * scale;
        }
    }
}

extern "C" void kernel_launch(void* const* d_in, const int* in_sizes, int n_in,
                              void* d_out, int out_size, void* d_ws, size_t ws_size,
                              hipStream_t stream) {
    const float* in   = (const float*)d_in[0];
    const float* kern = (const float*)d_in[1];
    float* out        = (float*)d_out;

    dim3 grid(B * (H / 2) * (W / 16)), block(256);   // 4096 blocks, 32 px each
    hipLaunchKernelGGL(blur_fused, grid, block, 0, stream, in, kern, out);
}